// Round 1
// 243.070 us; speedup vs baseline: 1.3208x; 1.3208x over previous
//
#include <hip/hip_runtime.h>

// FourierFeatureMLP fused kernel for MI355X (gfx950). Round 6.
//
// vs round 5 (287 us steady; MfmaUtil 20.6%, VALUBusy 33%, LDS ~28%):
// pipes each <35% busy but summed ~85% -> barrier-lockstep serialization
// (16 waves alternate K-loop / tanh phases; co-resident blocks phase-lock).
// Fix: wave-autonomous structure. Each wave owns 32 points and computes
// ALL 256 units: h stays in VGPRs (B-frag layout, ping-pong h0/h1), the
// D-layout -> B-frag repack goes through a wave-private 4 KB LDS buffer
// (same-wave DS ops are in-order -> no barrier). ZERO __syncthreads.
// Weights pre-permuted to fragment-major order -> every a-load is a
// fully-coalesced dense b128 (frag*1024 + lane*16), pipelined 1 kt ahead.
//
// Layouts (MFMA 16x16x32, learn_hip-verified):
//   A: lane holds A[m=lane&15][k=quad*8+j]   (W fragment)
//   B: lane holds B[k=quad*8+j][n=lane&15]   (h fragment, n = point)
//   D: n(point)=lane&15, m(unit)=quad*4+reg
//
// Repack: chunk c outputs units u'=mt*16+quad*4+r (D) -> next-layer k-tiles
// 2c,2c+1 need k=quad*8+j (B). Via LDS [32 pts][64 u] with 16B-chunk XOR
// swizzle c8' = c8 ^ (row&7): write half4 per (mt,nt), read half8 per
// (kp,nt). 8 writes + 4 reads per chunk, conflict-minimal.

#define HDIM   256
#define NFREQ  128
#define NLAYER 8
#define PTSW   32                  // points per wave
#define NTHR   256
#define TILE_N 128                 // 4 waves * 32 points
#define WHALVES (NLAYER * HDIM * HDIM)

typedef __attribute__((ext_vector_type(8))) _Float16 half8;
typedef __attribute__((ext_vector_type(4))) _Float16 half4;
typedef __attribute__((ext_vector_type(2))) _Float16 half2;
typedef __attribute__((ext_vector_type(4))) float float4v;

__device__ __forceinline__ half2 pk2(float a, float b) {
    return __builtin_bit_cast(half2, __builtin_amdgcn_cvt_pkrtz(a, b));
}

// tanh(acc + b) with pre-scaled bias bK = b * 2/ln2:
// t = acc*K + bK; z = 2^t; r = 1/(1+z); tanh = 1 - 2r. Saturation-safe.
#define TANH_K 2.885390081777927f
__device__ __forceinline__ float fast_tanh_fused(float acc, float bK) {
    float z = __builtin_amdgcn_exp2f(fmaf(acc, TANH_K, bK));
    float r = __builtin_amdgcn_rcpf(z + 1.0f);
    return fmaf(-2.0f, r, 1.0f);
}

// ---- pre-pass: fp32 -> fp16 weights, permuted to FRAGMENT-major order.
// dst half index i: j=i&7, lane=(i>>3)&63, frag=i>>9;
// frag = ((layer*4 + c)*4 + mt)*8 + kt. Each 1 KB frag is one wave a-load.
__global__ void convert_w_kernel(const float* __restrict__ W_in,
                                 const float* __restrict__ W_h,
                                 _Float16* __restrict__ dst)
{
    const int i = blockIdx.x * blockDim.x + threadIdx.x;   // 0 .. WHALVES-1
    const int j     = i & 7;
    const int lane  = (i >> 3) & 63;
    const int frag  = i >> 9;
    const int kt    = frag & 7;
    const int mt    = (frag >> 3) & 3;
    const int c     = (frag >> 5) & 3;
    const int layer = frag >> 7;
    const int u = c * 64 + mt * 16 + (lane & 15);
    const int k = kt * 32 + (lane >> 4) * 8 + j;
    const float v = (layer == 0) ? W_in[u * HDIM + k]
                                 : W_h[((layer - 1) * HDIM + u) * HDIM + k];
    dst[i] = (_Float16)v;
}

// One dense layer for one wave: hin (B-frags, regs) -> hout (B-frags, regs).
// wl = fragment-major weight base for this layer, pre-offset by lane*8.
__device__ __forceinline__ void layer_step(const _Float16* __restrict__ wl,
                                           const float* __restrict__ bl,
                                           _Float16* __restrict__ lds0,
                                           _Float16* __restrict__ lds1,
                                           const int laneM, const int quad,
                                           const half8 (&hin)[2][8],
                                           half8 (&hout)[2][8])
{
    half8 a[4];
    #pragma unroll
    for (int mt = 0; mt < 4; ++mt)                 // preload chunk 0, kt 0
        a[mt] = *(const half8*)&wl[(mt * 8) * 512];

    #pragma unroll
    for (int c = 0; c < 4; ++c) {
        _Float16* __restrict__ lds = (c & 1) ? lds1 : lds0;

        float4v acc[4][2];
        #pragma unroll
        for (int mt = 0; mt < 4; ++mt)
            #pragma unroll
            for (int nt = 0; nt < 2; ++nt)
                acc[mt][nt] = (float4v){0.f, 0.f, 0.f, 0.f};

        #pragma unroll
        for (int kt = 0; kt < 8; ++kt) {
            half8 an[4];
            if (kt < 7) {                          // next kt of this chunk
                #pragma unroll
                for (int mt = 0; mt < 4; ++mt)
                    an[mt] = *(const half8*)&wl[(c * 32 + mt * 8 + kt + 1) * 512];
            } else if (c < 3) {                    // kt 0 of next chunk
                #pragma unroll
                for (int mt = 0; mt < 4; ++mt)
                    an[mt] = *(const half8*)&wl[((c + 1) * 32 + mt * 8) * 512];
            }
            #pragma unroll
            for (int mt = 0; mt < 4; ++mt)
                #pragma unroll
                for (int nt = 0; nt < 2; ++nt)
                    acc[mt][nt] = __builtin_amdgcn_mfma_f32_16x16x32_f16(
                        a[mt], hin[nt][kt], acc[mt][nt], 0, 0, 0);
            if (kt < 7 || c < 3) {
                #pragma unroll
                for (int mt = 0; mt < 4; ++mt) a[mt] = an[mt];  // SSA rename
            }
        }

        // epilogue: bias+tanh, pack, wave-private repack through LDS
        #pragma unroll
        for (int mt = 0; mt < 4; ++mt) {
            const float4 b4 = *(const float4*)&bl[c * 64 + mt * 16 + quad * 4];
            const float bx = b4.x * TANH_K, by = b4.y * TANH_K;
            const float bz = b4.z * TANH_K, bw = b4.w * TANH_K;
            const int c8 = mt * 2 + (quad >> 1);
            #pragma unroll
            for (int nt = 0; nt < 2; ++nt) {
                const int row = nt * 16 + laneM;
                const float v0 = fast_tanh_fused(acc[mt][nt].x, bx);
                const float v1 = fast_tanh_fused(acc[mt][nt].y, by);
                const float v2 = fast_tanh_fused(acc[mt][nt].z, bz);
                const float v3 = fast_tanh_fused(acc[mt][nt].w, bw);
                const half2 lo = pk2(v0, v1);
                const half2 hi = pk2(v2, v3);
                half4 pkv;
                pkv.x = lo.x; pkv.y = lo.y; pkv.z = hi.x; pkv.w = hi.y;
                *(half4*)&lds[row * 64 + ((c8 ^ (row & 7)) << 3) + (quad & 1) * 4] = pkv;
            }
        }
        // read back as B-frags for next layer (same wave: DS is in-order)
        #pragma unroll
        for (int kp = 0; kp < 2; ++kp)
            #pragma unroll
            for (int nt = 0; nt < 2; ++nt) {
                const int row = nt * 16 + laneM;
                const int c8r = (kp * 4 + quad) ^ (row & 7);
                hout[nt][c * 2 + kp] = *(const half8*)&lds[row * 64 + (c8r << 3)];
            }
    }
}

__device__ __forceinline__ float dot8(const half8 h, const float4 wa, const float4 wb) {
    return (float)h[0]*wa.x + (float)h[1]*wa.y + (float)h[2]*wa.z + (float)h[3]*wa.w
         + (float)h[4]*wb.x + (float)h[5]*wb.y + (float)h[6]*wb.z + (float)h[7]*wb.w;
}

__global__ __launch_bounds__(NTHR, 2)
void ffmlp_kernel(const float* __restrict__ tx,
                  const float* __restrict__ Bf,
                  const _Float16* __restrict__ Wall,
                  const float* __restrict__ b_in,
                  const float* __restrict__ b_h,
                  const float* __restrict__ W_out,
                  const float* __restrict__ b_out,
                  float* __restrict__ out)
{
    // 4 waves x 2 chunk-parity buffers x (32 pts x 64 units) fp16 = 32 KB
    __shared__ __align__(16) _Float16 lbuf[4][2][PTSW * 64];

    const int tid   = threadIdx.x;
    const int wave  = tid >> 6;
    const int lane  = tid & 63;
    const int laneM = lane & 15;
    const int quad  = lane >> 4;
    const int p0    = blockIdx.x * TILE_N + wave * PTSW;   // wave's first point

    half8 h0[2][8], h1[2][8];

    // -------- stage 1: Fourier features directly into B-frag registers ----
    // k = kq*32 + quad*8 + j ; kq 0..3 -> sin(f=k), kq+4 -> cos(f=k).
    // sin(2*pi*r) = v_sin(fract(r)) : argument in revolutions.
    {
        const float2* txv = (const float2*)tx;
        const float2* Bv  = (const float2*)Bf;
        #pragma unroll
        for (int nt = 0; nt < 2; ++nt) {
            const float2 t = txv[p0 + nt * 16 + laneM];
            #pragma unroll
            for (int kq = 0; kq < 4; ++kq) {
                const int f0 = kq * 32 + quad * 8;
                half8 s8, c8v;
                #pragma unroll
                for (int jj = 0; jj < 8; jj += 2) {
                    const float2 bA = Bv[f0 + jj];
                    const float2 bB = Bv[f0 + jj + 1];
                    const float r0 = __builtin_amdgcn_fractf(t.x * bA.x + t.y * bA.y);
                    const float r1 = __builtin_amdgcn_fractf(t.x * bB.x + t.y * bB.y);
                    const half2 sp = pk2(__builtin_amdgcn_sinf(r0), __builtin_amdgcn_sinf(r1));
                    const half2 cp = pk2(__builtin_amdgcn_cosf(r0), __builtin_amdgcn_cosf(r1));
                    s8[jj] = sp.x;  s8[jj + 1] = sp.y;
                    c8v[jj] = cp.x; c8v[jj + 1] = cp.y;
                }
                h0[nt][kq]     = s8;
                h0[nt][kq + 4] = c8v;
            }
        }
    }

    // -------- stage 2: 8 dense layers, fully wave-local, NO barriers ------
    _Float16* __restrict__ lds0 = &lbuf[wave][0][0];
    _Float16* __restrict__ lds1 = &lbuf[wave][1][0];
    #pragma unroll 1
    for (int lp = 0; lp < 4; ++lp) {
        const int la = 2 * lp, lb = 2 * lp + 1;
        const float* bla = (la == 0) ? b_in : b_h + (la - 1) * HDIM;
        const float* blb = b_h + (lb - 1) * HDIM;
        layer_step(Wall + la * (HDIM * HDIM) + lane * 8, bla,
                   lds0, lds1, laneM, quad, h0, h1);
        layer_step(Wall + lb * (HDIM * HDIM) + lane * 8, blb,
                   lds0, lds1, laneM, quad, h1, h0);
    }

    // -------- stage 3: output matvec from registers ------------------------
    {
        float s0 = 0.f, s1 = 0.f;
        #pragma unroll
        for (int kt = 0; kt < 8; ++kt) {
            const float4 wa = *(const float4*)&W_out[kt * 32 + quad * 8];
            const float4 wb = *(const float4*)&W_out[kt * 32 + quad * 8 + 4];
            s0 += dot8(h0[0][kt], wa, wb);
            s1 += dot8(h0[1][kt], wa, wb);
        }
        s0 += __shfl_xor(s0, 16); s0 += __shfl_xor(s0, 32);
        s1 += __shfl_xor(s1, 16); s1 += __shfl_xor(s1, 32);
        if (quad == 0) {
            const float bo = b_out[0];
            out[p0 + laneM]      = s0 + bo;
            out[p0 + 16 + laneM] = s1 + bo;
        }
    }
}

extern "C" void kernel_launch(void* const* d_in, const int* in_sizes, int n_in,
                              void* d_out, int out_size, void* d_ws, size_t ws_size,
                              hipStream_t stream) {
    const float* tx    = (const float*)d_in[0];
    const float* Bf    = (const float*)d_in[1];
    const float* W_in  = (const float*)d_in[2];
    const float* b_in  = (const float*)d_in[3];
    const float* W_h   = (const float*)d_in[4];
    const float* b_h   = (const float*)d_in[5];
    const float* W_out = (const float*)d_in[6];
    const float* b_out = (const float*)d_in[7];
    float* out = (float*)d_out;

    _Float16* Wall = (_Float16*)d_ws;   // 1 MiB scratch, fragment-major

    const int npts   = in_sizes[0] / 2;
    const int blocks = npts / TILE_N;   // 1024

    convert_w_kernel<<<WHALVES / NTHR, NTHR, 0, stream>>>(W_in, W_h, Wall);
    ffmlp_kernel<<<blocks, NTHR, 0, stream>>>(tx, Bf, Wall, b_in, b_h,
                                              W_out, b_out, out);
}